// Round 3
// baseline (972.193 us; speedup 1.0000x reference)
//
#include <hip/hip_runtime.h>

// ---------------- workspace layout (float offsets) ----------------
#define OFF_X     0          // x_flat [32][46656]
#define OFF_CUR1  1492992    // [32][1000]
#define OFF_MEM1  1524992
#define OFF_MEM2  1556992
#define OFF_MEM3  1588992
#define OFF_SPK1B 1652992
#define OFF_SPK2  1684992
#define OFF_SPK3  1716992
#define OFF_K     1780992
#define OFF_V     1812992
#define OFF_MEMR  1844992    // [32][100]
#define OFF_SPKR  1848192    // [32][100]
#define OFF_MEMO  1851392    // [32]
#define OFF_PATT  1851424    // [32][8] attention partial sums
#define OFF_CNT   1851680    // [5][4] spike counters
#define OFF_OACC  1851700    // [32]
#define OFF_SC    1851732    // total, reg
#define OFF_PART  1851744    // gemm1 partials [nchunk][32][1000]

static constexpr float kBETA  = 0.8f;
static constexpr float kTHR   = 0.5f;
static constexpr float kBETAR = 0.95f;
static constexpr float kTHRR  = 1.0f;
static constexpr float kLM    = 0.0058f;

// ---------------- init: zero all persistent state ----------------
__global__ void k_init(float* ws) {
    int idx = blockIdx.x * 256 + threadIdx.x;
    if (idx < 96000) {
        ws[OFF_MEM1 + idx] = 0.f;                 // mem1, mem2, mem3 (contiguous)
    } else {
        int j = idx - 96000;
        if (j < 6744) ws[OFF_MEMR + j] = 0.f;     // mem_r..sc region (contiguous)
    }
}

// ---------------- patch embed: x = patches @ W_pe + b_pe + pos ----------------
__global__ __launch_bounds__(64) void k_patch(
    const float* __restrict__ data, const float* __restrict__ Wpe,
    const float* __restrict__ bpe, const float* __restrict__ pos,
    float* __restrict__ xf)
{
    int bp = blockIdx.x;
    int b = bp / 729, p = bp % 729;
    int pr = p / 27, pc = p % 27;
    int tid = threadIdx.x;
    __shared__ float patch[256];
    const float* db = data + (size_t)b * 50176;
    for (int c = tid; c < 256; c += 64) {
        int ph = c >> 4, pw = c & 15;
        patch[c] = db[(pr * 8 + ph) * 224 + pc * 8 + pw];
    }
    __syncthreads();
    float acc = bpe[tid] + pos[p * 64 + tid];
    for (int c = 0; c < 256; ++c)
        acc = fmaf(patch[c], Wpe[c * 64 + tid], acc);
    xf[(size_t)b * 46656 + p * 64 + tid] = acc;
}

// ---------------- big GEMM partials: cur1 += x_flat @ W1 (chunked over K) ----------------
// grid (nchunk, 2 hgroups, 2 bgroups): hg covers h [hg*500,+500), bg covers batches [bg*16,+16).
// acc[16][2] = 32 VGPR accumulators -> ~5.7 waves/SIMD at 1460 blocks.
// h-split (not more b-split) keeps W1 logical reads at 2x (hg blocks read DISJOINT W1 columns).
__global__ __launch_bounds__(256) void k_gemm1_part(
    const float* __restrict__ xf, const float* __restrict__ W1,
    float* __restrict__ part, int tpc)
{
    int chunk = blockIdx.x;
    int hg = blockIdx.y;
    int bg = blockIdx.z;
    int t0 = chunk * tpc;
    int t1 = t0 + tpc; if (t1 > 729) t1 = 729;
    int tid = threadIdx.x;
    __shared__ float xs[1024];           // [16 b][64 i]
    float acc[16][2];
    #pragma unroll
    for (int b = 0; b < 16; ++b) { acc[b][0] = 0.f; acc[b][1] = 0.f; }

    const size_t bbase = (size_t)(bg * 16) * 46656;
    const int hbase = hg * 500;
    for (int tt = t0; tt < t1; ++tt) {
        int i0 = tt * 64;
        __syncthreads();
        for (int l = tid; l < 1024; l += 256)
            xs[l] = xf[bbase + (size_t)(l >> 6) * 46656 + i0 + (l & 63)];
        __syncthreads();
        for (int ii4 = 0; ii4 < 16; ++ii4) {
            int i = i0 + ii4 * 4;
            float w0[2], w1v[2], w2[2], w3[2];
            #pragma unroll
            for (int j = 0; j < 2; ++j) {
                int hh = tid + j * 256;
                bool ok = hh < 500;
                const float* col = W1 + (size_t)i * 1000 + hbase + (ok ? hh : 0);
                w0[j]  = ok ? col[0]    : 0.f;
                w1v[j] = ok ? col[1000] : 0.f;
                w2[j]  = ok ? col[2000] : 0.f;
                w3[j]  = ok ? col[3000] : 0.f;
            }
            #pragma unroll
            for (int b = 0; b < 16; ++b) {
                float4 xv = *reinterpret_cast<const float4*>(&xs[b * 64 + ii4 * 4]);
                #pragma unroll
                for (int j = 0; j < 2; ++j) {
                    float a = acc[b][j];
                    a = fmaf(xv.x, w0[j],  a);
                    a = fmaf(xv.y, w1v[j], a);
                    a = fmaf(xv.z, w2[j],  a);
                    a = fmaf(xv.w, w3[j],  a);
                    acc[b][j] = a;
                }
            }
        }
    }
    float* pc = part + (size_t)chunk * 32000;
    for (int b = 0; b < 16; ++b)
        #pragma unroll
        for (int j = 0; j < 2; ++j) {
            int hh = tid + j * 256;
            if (hh < 500) pc[(bg * 16 + b) * 1000 + hbase + hh] = acc[b][j];
        }
}

__global__ void k_gemm1_reduce(const float* __restrict__ part,
                               const float* __restrict__ b1,
                               float* __restrict__ cur1, int nchunk)
{
    int idx = blockIdx.x * 256 + threadIdx.x;
    if (idx >= 32000) return;
    int h = idx % 1000;
    float a = b1[h];
    for (int c = 0; c < nchunk; ++c) a += part[(size_t)c * 32000 + idx];
    cur1[idx] = a;
}

// ---------------- fused stepA (double leaky) + RLeaky, one block per batch ----------------
// spk1 never leaves the block: staged in LDS for the WR-GEMM; count done in-block.
__global__ __launch_bounds__(256) void k_stepR(
    const float* __restrict__ cur1, float* __restrict__ mem1,
    float* __restrict__ spk1b,
    const float* __restrict__ WR, const float* __restrict__ bR,
    const float* __restrict__ Vw, const float* __restrict__ Vb,
    float* __restrict__ mem_r, float* __restrict__ spk_r,
    float* cnt0, float* cnt2)
{
    int b = blockIdx.x;
    int tid = threadIdx.x;
    __shared__ float s1[1000];
    __shared__ float sr[100];
    __shared__ float red2[2][128];
    __shared__ float csum[4];

    // phase 1: double leaky on 1000 elems (250 threads x 4, vectorized)
    float localc = 0.f;
    if (tid < 250) {
        int base = b * 1000 + tid * 4;
        float4 m4 = *reinterpret_cast<const float4*>(&mem1[base]);
        float4 c4 = *reinterpret_cast<const float4*>(&cur1[base]);
        float mm[4] = {m4.x, m4.y, m4.z, m4.w};
        float cc[4] = {c4.x, c4.y, c4.z, c4.w};
        float mb[4], sb[4];
        #pragma unroll
        for (int q = 0; q < 4; ++q) {
            float m = mm[q], c = cc[q];
            float r1 = (m - kTHR > 0.f) ? kTHR : 0.f;
            float ma = __fsub_rn(__fadd_rn(__fmul_rn(kBETA, m), c), r1);
            float s  = (ma - kTHR > 0.f) ? 1.f : 0.f;
            float r2 = __fmul_rn(s, kTHR);
            float mv = __fsub_rn(__fadd_rn(__fmul_rn(kBETA, ma), c), r2);
            sb[q] = (mv - kTHR > 0.f) ? 1.f : 0.f;
            mb[q] = mv;
            s1[tid * 4 + q] = s;
            localc += s;
        }
        *reinterpret_cast<float4*>(&mem1[base])  = make_float4(mb[0], mb[1], mb[2], mb[3]);
        *reinterpret_cast<float4*>(&spk1b[base]) = make_float4(sb[0], sb[1], sb[2], sb[3]);
    }
    if (tid < 100) sr[tid] = spk_r[b * 100 + tid];
    // in-wave count reduce
    for (int off = 32; off; off >>= 1) localc += __shfl_down(localc, off, 64);
    if ((tid & 63) == 0) csum[tid >> 6] = localc;
    __syncthreads();
    if (tid == 0) atomicAdd(cnt0, csum[0] + csum[1] + csum[2] + csum[3]);

    // phase 2: rlin = s1 @ WR (K split 2-way), rec = sr @ Vw, RLeaky update
    int ks = tid >> 7, hh = tid & 127;
    float p = 0.f;
    if (hh < 100) {
        const float* wp = WR + (size_t)(ks * 500) * 100 + hh;
        int j0 = ks * 500;
        #pragma unroll 4
        for (int j = 0; j < 500; ++j) p = fmaf(s1[j0 + j], wp[(size_t)j * 100], p);
    }
    red2[ks][hh] = p;
    __syncthreads();
    float s = 0.f;
    if (tid < 100) {
        float acc = bR[tid] + red2[0][tid] + red2[1][tid];
        float rec = 0.f;
        for (int j = 0; j < 100; ++j) rec = fmaf(sr[j], Vw[j * 100 + tid], rec);
        float m = mem_r[b * 100 + tid];
        float r = (m - kTHRR > 0.f) ? kTHRR : 0.f;
        float mn = __fsub_rn(__fadd_rn(__fadd_rn(__fadd_rn(__fmul_rn(kBETAR, m), acc), rec), Vb[tid]), r);
        s = (mn - kTHRR > 0.f) ? 1.f : 0.f;
        mem_r[b * 100 + tid] = mn;
        spk_r[b * 100 + tid] = s;
    }
    unsigned long long msk = __ballot(s > 0.5f);
    if ((tid & 63) == 0) atomicAdd(cnt2, (float)__popcll(msk));
}

// ---------------- fused spike-GEMM: in-kernel split-K + LDS reduce + leaky epilogue ----------------
// grid (8 hblk, 32 batch), 512 thr = 4 K-slices x 128 h-lanes. No partial buffers.
template <bool LEAKY, bool COUNT>
__global__ __launch_bounds__(512) void k_gemmF(
    const float* __restrict__ A, const float* __restrict__ W,
    const float* __restrict__ bias, float* __restrict__ mem,
    float* __restrict__ out, float* cnt, float beta, float thr)
{
    int hb = blockIdx.x, b = blockIdx.y;
    int tid = threadIdx.x;
    __shared__ float al[1000];
    __shared__ float red[4][128];
    for (int l = tid; l < 1000; l += 512) al[l] = A[b * 1000 + l];
    __syncthreads();
    int ks = tid >> 7, hh = tid & 127;
    float acc = 0.f;
    if (hh < 125) {
        int h = hb * 125 + hh;
        const float* wp = W + (size_t)(ks * 250) * 1000 + h;
        int j0 = ks * 250;
        #pragma unroll 5
        for (int j = 0; j < 250; ++j)
            acc = fmaf(al[j0 + j], wp[(size_t)j * 1000], acc);
    }
    red[ks][hh] = acc;
    __syncthreads();
    float s = 0.f;
    if (tid < 125) {
        int h = hb * 125 + tid;
        int idx = b * 1000 + h;
        float a = bias[h] + ((red[0][tid] + red[1][tid]) + (red[2][tid] + red[3][tid]));
        if (LEAKY) {
            float m = mem[idx];
            float r = (m - thr > 0.f) ? thr : 0.f;
            float mn = __fsub_rn(__fadd_rn(__fmul_rn(beta, m), a), r);
            mem[idx] = mn;
            s = (mn - thr > 0.f) ? 1.f : 0.f;
            out[idx] = s;
        } else {
            out[idx] = a;
        }
    }
    if (COUNT) {
        unsigned long long msk = __ballot(s > 0.5f);
        if ((tid & 63) == 0) atomicAdd(cnt, (float)__popcll(msk));
    }
}

// dual-weight variant for k/v
__global__ __launch_bounds__(512) void k_gemmF_kv(
    const float* __restrict__ A, const float* __restrict__ Wk,
    const float* __restrict__ bk, const float* __restrict__ Wv,
    const float* __restrict__ bv, float* __restrict__ ko, float* __restrict__ vo)
{
    int hb = blockIdx.x, b = blockIdx.y;
    int tid = threadIdx.x;
    __shared__ float al[1000];
    __shared__ float redk[4][128];
    __shared__ float redv[4][128];
    for (int l = tid; l < 1000; l += 512) al[l] = A[b * 1000 + l];
    __syncthreads();
    int ks = tid >> 7, hh = tid & 127;
    float ak = 0.f, av = 0.f;
    if (hh < 125) {
        int h = hb * 125 + hh;
        const float* wkp = Wk + (size_t)(ks * 250) * 1000 + h;
        const float* wvp = Wv + (size_t)(ks * 250) * 1000 + h;
        int j0 = ks * 250;
        #pragma unroll 5
        for (int j = 0; j < 250; ++j) {
            float a = al[j0 + j];
            ak = fmaf(a, wkp[(size_t)j * 1000], ak);
            av = fmaf(a, wvp[(size_t)j * 1000], av);
        }
    }
    redk[ks][hh] = ak;
    redv[ks][hh] = av;
    __syncthreads();
    if (tid < 125) {
        int h = hb * 125 + tid;
        int idx = b * 1000 + h;
        ko[idx] = bk[h] + ((redk[0][tid] + redk[1][tid]) + (redk[2][tid] + redk[3][tid]));
        vo[idx] = bv[h] + ((redv[0][tid] + redv[1][tid]) + (redv[2][tid] + redv[3][tid]));
    }
}

// ---------------- attention (q fused): q_i = spkr@Wq+bq; softmax_j(q_i*k_j/scale).v ----------------
__global__ __launch_bounds__(128) void k_attn(
    const float* __restrict__ spkr, const float* __restrict__ Wq,
    const float* __restrict__ bq, const float* __restrict__ kg,
    const float* __restrict__ vg, const float* __restrict__ Wo,
    float* __restrict__ part_att)
{
    int b = blockIdx.y;
    int it = blockIdx.x;
    int tid = threadIdx.x;
    __shared__ float kk[1000], vv[1000];
    __shared__ float sr[100];
    __shared__ float rmax[128], rmin[128], rsum[128];
    float pmax = -3.4e38f, pmin = 3.4e38f;
    if (tid < 100) sr[tid] = spkr[b * 100 + tid];
    for (int j = tid; j < 1000; j += 128) {
        float kj = kg[b * 1000 + j];
        kk[j] = kj;
        vv[j] = vg[b * 1000 + j];
        pmax = fmaxf(pmax, kj);
        pmin = fminf(pmin, kj);
    }
    rmax[tid] = pmax; rmin[tid] = pmin;
    __syncthreads();
    for (int s2 = 64; s2 > 0; s2 >>= 1) {
        if (tid < s2) {
            rmax[tid] = fmaxf(rmax[tid], rmax[tid + s2]);
            rmin[tid] = fminf(rmin[tid], rmin[tid + s2]);
        }
        __syncthreads();
    }
    float kmax = rmax[0], kmin = rmin[0];
    float pw = 0.f;
    int i = it * 125 + tid;
    if (tid < 125) {
        float qi = bq[i];
        for (int j = 0; j < 100; ++j) qi = fmaf(sr[j], Wq[j * 1000 + i], qi);
        float qs = qi / 31.62277660168379f;   // sqrt(1000)
        float m = (qs >= 0.f) ? qs * kmax : qs * kmin;
        float den = 0.f, num = 0.f;
        for (int j = 0; j < 1000; ++j) {
            float e = __expf(fmaf(qs, kk[j], -m));
            den += e;
            num = fmaf(e, vv[j], num);
        }
        pw = (num / den) * Wo[i];
    }
    __syncthreads();
    rsum[tid] = pw;
    __syncthreads();
    for (int s2 = 64; s2 > 0; s2 >>= 1) {
        if (tid < s2) rsum[tid] += rsum[tid + s2];
        __syncthreads();
    }
    if (tid == 0) part_att[b * 8 + it] = rsum[0];
}

// ---------------- finalize: mem_out leaky, totals, reg, outputs ----------------
__global__ void k_final(const float* __restrict__ part_att, const float* __restrict__ bo,
                        float* __restrict__ mem_out, float* __restrict__ out_acc,
                        const float* __restrict__ cnt, float* __restrict__ sc,
                        float* __restrict__ dout, int t)
{
    int tid = threadIdx.x;   // 64 threads, one wave
    float s = 0.f;
    if (tid < 32) {
        float a = bo[0];
        for (int it = 0; it < 8; ++it) a += part_att[tid * 8 + it];
        float m = mem_out[tid];
        float r = (m - kTHR > 0.f) ? kTHR : 0.f;
        float mn = __fsub_rn(__fadd_rn(__fmul_rn(kBETA, m), a), r);
        mem_out[tid] = mn;
        s = (mn - kTHR > 0.f) ? 1.f : 0.f;
        float oa = out_acc[tid] + s;
        out_acc[tid] = oa;
        if (t == 4) dout[tid] = oa / 5.0f;
    }
    unsigned long long msk = __ballot(s > 0.5f);
    float co = (float)__popcll(msk);
    if (tid == 0) {
        float total = sc[0];
        float prev = total;
        total = __fadd_rn(total, __fdiv_rn(cnt[0], 32000.f));
        total = __fadd_rn(total, __fdiv_rn(cnt[1], 32000.f));
        total = __fadd_rn(total, __fdiv_rn(cnt[2], 3200.f));
        total = __fadd_rn(total, __fdiv_rn(co, 32.f));
        float reg = sc[1];
        reg = __fadd_rn(reg, __fmul_rn(kLM, total));
        if (t > 0) reg = __fadd_rn(reg, __fmul_rn(kLM, fabsf(__fsub_rn(total, prev))));
        sc[0] = total; sc[1] = reg;
        if (t == 4) dout[32] = reg / 5.0f;
    }
}

// ---------------- host ----------------
extern "C" void kernel_launch(void* const* d_in, const int* in_sizes, int n_in,
                              void* d_out, int out_size, void* d_ws, size_t ws_size,
                              hipStream_t stream)
{
    const float* data = (const float*)d_in[0];
    const float* Wpe  = (const float*)d_in[1];
    const float* bpe  = (const float*)d_in[2];
    const float* pos  = (const float*)d_in[3];
    const float* W1   = (const float*)d_in[4];
    const float* b1   = (const float*)d_in[5];
    const float* W2   = (const float*)d_in[6];
    const float* b2   = (const float*)d_in[7];
    const float* W3   = (const float*)d_in[8];
    const float* b3   = (const float*)d_in[9];
    const float* WR   = (const float*)d_in[10];
    const float* bR   = (const float*)d_in[11];
    const float* Vw   = (const float*)d_in[12];
    const float* Vb   = (const float*)d_in[13];
    const float* Wq   = (const float*)d_in[14];
    const float* bq   = (const float*)d_in[15];
    const float* Wk   = (const float*)d_in[16];
    const float* bk   = (const float*)d_in[17];
    const float* Wv   = (const float*)d_in[18];
    const float* bv   = (const float*)d_in[19];
    const float* Wo   = (const float*)d_in[20];
    const float* bo   = (const float*)d_in[21];

    float* ws = (float*)d_ws;
    float* dout = (float*)d_out;

    float* xf    = ws + OFF_X;
    float* cur1  = ws + OFF_CUR1;
    float* mem1  = ws + OFF_MEM1;
    float* mem2  = ws + OFF_MEM2;
    float* mem3  = ws + OFF_MEM3;
    float* spk1b = ws + OFF_SPK1B;
    float* spk2  = ws + OFF_SPK2;
    float* spk3  = ws + OFF_SPK3;
    float* kb_   = ws + OFF_K;
    float* vb_   = ws + OFF_V;
    float* memr  = ws + OFF_MEMR;
    float* spkr  = ws + OFF_SPKR;
    float* memo  = ws + OFF_MEMO;
    float* patt  = ws + OFF_PATT;
    float* cntb  = ws + OFF_CNT;
    float* oacc  = ws + OFF_OACC;
    float* sc    = ws + OFF_SC;
    float* part  = ws + OFF_PART;

    // chunk count for the big GEMM, sized from available workspace.
    size_t ws_f = ws_size / 4;
    size_t avail = (ws_f > OFF_PART) ? (ws_f - OFF_PART) : 0;
    long nchunk_l = (long)(avail / 32000);
    int nchunk = (nchunk_l > 365) ? 365 : (int)nchunk_l;
    if (nchunk < 1) nchunk = 1;
    int tpc = (729 + nchunk - 1) / nchunk;
    nchunk = (729 + tpc - 1) / tpc;

    k_init<<<402, 256, 0, stream>>>(ws);
    k_patch<<<23328, 64, 0, stream>>>(data, Wpe, bpe, pos, xf);
    k_gemm1_part<<<dim3(nchunk, 2, 2), 256, 0, stream>>>(xf, W1, part, tpc);
    k_gemm1_reduce<<<125, 256, 0, stream>>>(part, b1, cur1, nchunk);

    for (int t = 0; t < 5; ++t) {
        float* cnt = cntb + t * 4;
        // fused stepA + RLeaky (spk1 stays in LDS)
        k_stepR<<<32, 256, 0, stream>>>(cur1, mem1, spk1b, WR, bR, Vw, Vb,
                                        memr, spkr, cnt + 0, cnt + 2);
        // layer 2: spk1b @ W2 -> leaky -> spk2
        k_gemmF<true, false><<<dim3(8, 32), 512, 0, stream>>>(
            spk1b, W2, b2, mem2, spk2, nullptr, kBETA, kTHR);
        // layer 3: spk2 @ W3 -> leaky -> spk3 (+count)
        k_gemmF<true, true><<<dim3(8, 32), 512, 0, stream>>>(
            spk2, W3, b3, mem3, spk3, cnt + 1, kBETA, kTHR);
        // k/v: spk3 @ Wk, Wv
        k_gemmF_kv<<<dim3(8, 32), 512, 0, stream>>>(spk3, Wk, bk, Wv, bv, kb_, vb_);
        // attention with fused q-GEMM
        k_attn<<<dim3(8, 32), 128, 0, stream>>>(spkr, Wq, bq, kb_, vb_, Wo, patt);
        k_final<<<1, 64, 0, stream>>>(patt, bo, memo, oacc, cnt, sc, dout, t);
    }
    (void)in_sizes; (void)n_in; (void)out_size;
}